// Round 5
// baseline (73.946 us; speedup 1.0000x reference)
//
#include <hip/hip_runtime.h>

#define EPS_F 1e-6f
#define LOG2E 1.4426950408889634f

typedef float f4a __attribute__((ext_vector_type(4), aligned(16)));

// Force a (known-uniform) float into an SGPR.
__device__ __forceinline__ float rfl(float x) {
    return __builtin_bit_cast(float, __builtin_amdgcn_readfirstlane(__builtin_bit_cast(int, x)));
}

// Kernel 1: partial sums.
// grid = 1024 = B(8) x m-tiles(8, 128 m each) x n-chunks(16, 64 n each);
// block = 256 thr = 4 waves. Each lane owns TWO m's (m0 = lane, m1 = lane+64
// within the tile) -> one row-broadcast serves 128 m's, halving ds_read count
// vs 1 m/lane. Waves split the 64-n chunk 4 ways (16 n each). feat/xa rows
// staged once in LDS padded to 20 floats (80 B stride -> all b128 reads 16 B
// aligned; xa packed at +16). Inner-loop ds_reads are all-lanes-same-address
// broadcasts. 4-wave partials combined in LDS; 16 slices stored to d_ws.
__global__ __launch_bounds__(256, 4) void icgp_partial_kernel(
    const float* __restrict__ xa,       // (B, 1024, 1, 3)
    const float* __restrict__ feat,     // (B, 1024, 5, 3)
    const float* __restrict__ xt,       // (B, 1024, 1, 3)
    const float* __restrict__ log_std,  // (1, 5, 3)
    float* __restrict__ pws)            // (16, B*1024*15) partials
{
    // staging: 64 rows x 20 floats = 1280; epilogue: 4 x 1920 = 7680 floats.
    __shared__ float lds[7680];         // 30720 B

    const int bid  = blockIdx.x;
    const int nsb  = bid & 15;          // n-chunk (64 n's)
    const int mt   = (bid >> 4) & 7;    // m-tile (128 m's)
    const int b    = bid >> 7;
    const int tid  = threadIdx.x;
    const int wv   = tid >> 6;          // 0..3
    const int lane = tid & 63;
    const int n0   = nsb * 64;

    // ---- stage feat (960 fl) and xa (192 fl) into padded rows ----
    const float* __restrict__ fg = feat + ((size_t)b * 1024 + n0) * 15; // 16B-aligned
    if (tid < 240) {
        const f4a v = *(const f4a*)(fg + tid * 4);
        #pragma unroll
        for (int e = 0; e < 4; ++e) {
            const int g = tid * 4 + e;
            const int r = g / 15, c = g - r * 15;
            lds[r * 20 + c] = v[e];
        }
    }
    const float* __restrict__ ag = xa + ((size_t)b * 1024 + n0) * 3;    // 16B-aligned
    if (tid < 48) {
        const f4a v = *(const f4a*)(ag + tid * 4);
        #pragma unroll
        for (int e = 0; e < 4; ++e) {
            const int g = tid * 4 + e;
            const int r = g / 3, c = g - r * 3;
            lds[r * 20 + 16 + c] = v[e];
        }
    }

    // ---- coefficients: wt = exp2(coef*(xa-xt)^2), coef = -0.5*log2e/std^2 ----
    float coef[15];
    #pragma unroll
    for (int kc = 0; kc < 15; ++kc) {
        const float s = __expf(log_std[kc]) + EPS_F;
        coef[kc] = rfl(-0.5f * LOG2E / (s * s));
    }
    bool uni = true;
    #pragma unroll
    for (int k = 1; k < 5; ++k)
        #pragma unroll
        for (int c = 0; c < 3; ++c)
            uni = uni && (coef[k * 3 + c] == coef[c]);

    // Two target points per lane.
    const int m0 = mt * 128 + lane;
    const int m1 = m0 + 64;
    const float t00 = xt[(b * 1024 + m0) * 3 + 0];
    const float t01 = xt[(b * 1024 + m0) * 3 + 1];
    const float t02 = xt[(b * 1024 + m0) * 3 + 2];
    const float t10 = xt[(b * 1024 + m1) * 3 + 0];
    const float t11 = xt[(b * 1024 + m1) * 3 + 1];
    const float t12 = xt[(b * 1024 + m1) * 3 + 2];

    __syncthreads();

    float acc0[15], acc1[15];
    #pragma unroll
    for (int kc = 0; kc < 15; ++kc) { acc0[kc] = 0.0f; acc1[kc] = 0.0f; }

    const int rb = wv * 16;             // this wave's first row

    if (uni) {
        const float c0 = coef[0], c1 = coef[1], c2 = coef[2];
        #pragma unroll 4
        for (int i = 0; i < 16; ++i) {
            const float* __restrict__ row = &lds[(rb + i) * 20];
            const f4a fA = *(const f4a*)(row);        // kc 0..3
            const f4a fB = *(const f4a*)(row + 4);    // kc 4..7
            const f4a fC = *(const f4a*)(row + 8);    // kc 8..11
            const f4a fD = *(const f4a*)(row + 12);   // kc 12..14 (+pad)
            const f4a av = *(const f4a*)(row + 16);   // xa0,xa1,xa2 (+pad)
            float d0, d1, d2;
            d0 = av.x - t00; d0 *= d0;
            d1 = av.y - t01; d1 *= d1;
            d2 = av.z - t02; d2 *= d2;
            const float w00 = __builtin_amdgcn_exp2f(d0 * c0);
            const float w01 = __builtin_amdgcn_exp2f(d1 * c1);
            const float w02 = __builtin_amdgcn_exp2f(d2 * c2);
            d0 = av.x - t10; d0 *= d0;
            d1 = av.y - t11; d1 *= d1;
            d2 = av.z - t12; d2 *= d2;
            const float w10 = __builtin_amdgcn_exp2f(d0 * c0);
            const float w11 = __builtin_amdgcn_exp2f(d1 * c1);
            const float w12 = __builtin_amdgcn_exp2f(d2 * c2);
            acc0[0]  += w00 * fA.x;  acc0[1]  += w01 * fA.y;  acc0[2]  += w02 * fA.z;
            acc0[3]  += w00 * fA.w;  acc0[4]  += w01 * fB.x;  acc0[5]  += w02 * fB.y;
            acc0[6]  += w00 * fB.z;  acc0[7]  += w01 * fB.w;  acc0[8]  += w02 * fC.x;
            acc0[9]  += w00 * fC.y;  acc0[10] += w01 * fC.z;  acc0[11] += w02 * fC.w;
            acc0[12] += w00 * fD.x;  acc0[13] += w01 * fD.y;  acc0[14] += w02 * fD.z;
            acc1[0]  += w10 * fA.x;  acc1[1]  += w11 * fA.y;  acc1[2]  += w12 * fA.z;
            acc1[3]  += w10 * fA.w;  acc1[4]  += w11 * fB.x;  acc1[5]  += w12 * fB.y;
            acc1[6]  += w10 * fB.z;  acc1[7]  += w11 * fB.w;  acc1[8]  += w12 * fC.x;
            acc1[9]  += w10 * fC.y;  acc1[10] += w11 * fC.z;  acc1[11] += w12 * fC.w;
            acc1[12] += w10 * fD.x;  acc1[13] += w11 * fD.y;  acc1[14] += w12 * fD.z;
        }
    } else {
        // General path: 15 exps per (n, m) (correct for arbitrary log_std).
        for (int i = 0; i < 16; ++i) {
            const float* __restrict__ row = &lds[(rb + i) * 20];
            float fv[16];
            *(f4a*)(fv)      = *(const f4a*)(row);
            *(f4a*)(fv + 4)  = *(const f4a*)(row + 4);
            *(f4a*)(fv + 8)  = *(const f4a*)(row + 8);
            *(f4a*)(fv + 12) = *(const f4a*)(row + 12);
            const f4a av = *(const f4a*)(row + 16);
            float dd0[3], dd1[3];
            dd0[0] = av.x - t00; dd0[0] *= dd0[0];
            dd0[1] = av.y - t01; dd0[1] *= dd0[1];
            dd0[2] = av.z - t02; dd0[2] *= dd0[2];
            dd1[0] = av.x - t10; dd1[0] *= dd1[0];
            dd1[1] = av.y - t11; dd1[1] *= dd1[1];
            dd1[2] = av.z - t12; dd1[2] *= dd1[2];
            #pragma unroll
            for (int k = 0; k < 5; ++k)
                #pragma unroll
                for (int c = 0; c < 3; ++c) {
                    acc0[k * 3 + c] +=
                        __builtin_amdgcn_exp2f(dd0[c] * coef[k * 3 + c]) * fv[k * 3 + c];
                    acc1[k * 3 + c] +=
                        __builtin_amdgcn_exp2f(dd1[c] * coef[k * 3 + c]) * fv[k * 3 + c];
                }
        }
    }

    // ---- in-block combine of 4 wave-partials, plain stores to pws ----
    __syncthreads();                    // staging no longer needed
    #pragma unroll
    for (int kc = 0; kc < 15; ++kc) {
        lds[wv * 1920 + lane * 15 + kc]        = acc0[kc];   // 2-way: free
        lds[wv * 1920 + (64 + lane) * 15 + kc] = acc1[kc];
    }
    __syncthreads();

    float* __restrict__ pb = pws + (size_t)nsb * 122880
                                 + ((size_t)b * 1024 + mt * 128) * 15;
    #pragma unroll
    for (int j = 0; j < 8; ++j) {
        const int o = j * 256 + tid;            // 0..1919
        if (o < 1920) {
            float s = 0.0f;
            #pragma unroll
            for (int w = 0; w < 4; ++w)
                s += lds[w * 1920 + o];          // consecutive addr: free
            pb[o] = s;                           // coalesced
        }
    }
}

// Kernel 2: sum the 16 n-chunk slices. 122880 outputs, fully coalesced.
__global__ __launch_bounds__(256) void icgp_reduce_kernel(
    const float* __restrict__ pws, float* __restrict__ out)
{
    const int idx = blockIdx.x * 256 + threadIdx.x;   // < 122880
    float s = 0.0f;
    #pragma unroll
    for (int ns = 0; ns < 16; ++ns)
        s += pws[(size_t)ns * 122880 + idx];
    out[idx] = s;
}

extern "C" void kernel_launch(void* const* d_in, const int* in_sizes, int n_in,
                              void* d_out, int out_size, void* d_ws, size_t ws_size,
                              hipStream_t stream) {
    const float* xa      = (const float*)d_in[0];  // (8,1024,1,3)
    const float* feat    = (const float*)d_in[1];  // (8,1024,5,3)
    const float* xt      = (const float*)d_in[2];  // (8,1024,1,3)
    const float* log_std = (const float*)d_in[3];  // (1,5,3)
    float* out = (float*)d_out;                    // (8,1024,5,3)
    float* pws = (float*)d_ws;                     // 16 x 122880 floats = 7.9 MB

    icgp_partial_kernel<<<dim3(1024), dim3(256), 0, stream>>>(xa, feat, xt, log_std, pws);
    icgp_reduce_kernel<<<dim3(480), dim3(256), 0, stream>>>(pws, out);
}